// Round 2
// baseline (1145.461 us; speedup 1.0000x reference)
//
#include <hip/hip_runtime.h>
#include <hip/hip_bf16.h>

// MoE expert MLP, grouped-GEMM formulation, m97-style MFMA GEMMs:
//   - all operands pre-converted to bf16 (chunked weight scratch, reused on-stream)
//   - global_load_lds width=16 staging, XOR k-quad swizzle on the global side
//     so fragment ds_read_b128s are 2-way (free) instead of 8-way conflicted
//   - B-row sigma permutation so each lane owns 4 contiguous output columns

#define SS 8192
#define HD 1024
#define FD 4096
#define NE 8
#define TK 2
#define NP (SS * TK)
#define MAX_TILES (NP / 128 + NE)
#define ZS 2   // gemm2 K-split for grid size

typedef __bf16 bf16x8 __attribute__((ext_vector_type(8)));
typedef unsigned short us8 __attribute__((ext_vector_type(8)));
typedef float f32x4 __attribute__((ext_vector_type(4)));
typedef unsigned int u32;

static __device__ __forceinline__ unsigned short f2bf(float f) {
  union { float f; unsigned u; } v; v.f = f;
  return (unsigned short)((v.u + 0x7fffu + ((v.u >> 16) & 1u)) >> 16);  // RNE
}

static __device__ __forceinline__ bf16x8 frag_ld(const unsigned short* p) {
  union { us8 u; bf16x8 b; } v;
  v.u = *(const us8*)p;
  return v.b;
}

static __device__ __forceinline__ void gll16(const void* g, void* l) {
  __builtin_amdgcn_global_load_lds(
      (const __attribute__((address_space(1))) u32*)g,
      (__attribute__((address_space(3))) u32*)l, 16, 0, 0);
}

static __device__ __forceinline__ float silu(float v) {
  return v / (1.f + __expf(-v));
}

// sigma: B-row permutation within each 64-row half: sigma(h*64+16q+l) = h*64+4l+q
static __device__ __forceinline__ int sigma(int r) {
  return (r & 64) + ((r & 15) * 4) + ((r >> 4) & 3);
}

// ---------------- bucket building ----------------

__global__ void count_kernel(const int* __restrict__ topk_e, int* __restrict__ counts) {
  __shared__ int lc[NE];
  int tid = threadIdx.x;
  if (tid < NE) lc[tid] = 0;
  __syncthreads();
  atomicAdd(&lc[topk_e[blockIdx.x * 256 + tid]], 1);
  __syncthreads();
  if (tid < NE) atomicAdd(&counts[tid], lc[tid]);
}

__global__ void plan_kernel(const int* __restrict__ counts, int* __restrict__ offsets,
                            int* __restrict__ cursors, int* __restrict__ tile_expert,
                            int* __restrict__ tile_rowstart, int* __restrict__ total_tiles) {
  if (threadIdx.x != 0 || blockIdx.x != 0) return;
  int off = 0, tt = 0;
  for (int e = 0; e < NE; ++e) {
    offsets[e] = off;
    cursors[e] = off;
    int n = counts[e];
    int nt = (n + 127) >> 7;
    for (int i = 0; i < nt; ++i) {
      tile_expert[tt] = e;
      tile_rowstart[tt] = off + i * 128;
      ++tt;
    }
    off += n;
  }
  offsets[NE] = off;
  *total_tiles = tt;
}

__global__ void scatter_kernel(const int* __restrict__ topk_e, const float* __restrict__ topk_w,
                               int* __restrict__ cursors, int* __restrict__ row_token,
                               float* __restrict__ row_w) {
  __shared__ int lcnt[NE];
  __shared__ int lbase[NE];
  int tid = threadIdx.x;
  if (tid < NE) lcnt[tid] = 0;
  __syncthreads();
  int t = blockIdx.x * 256 + tid;
  int e = topk_e[t];
  int my = atomicAdd(&lcnt[e], 1);
  __syncthreads();
  if (tid < NE) lbase[tid] = atomicAdd(&cursors[tid], lcnt[tid]);
  __syncthreads();
  row_token[lbase[e] + my] = t / TK;
  row_w[lbase[e] + my] = topk_w[t];
}

// ---------------- fp32 -> bf16 converts ----------------

__global__ void conv_x_kernel(const float* __restrict__ x, unsigned short* __restrict__ xb) {
  int i = blockIdx.x * 256 + threadIdx.x;      // one thread per 8 floats
  const float4* s = (const float4*)(x + (size_t)i * 8);
  float4 a = s[0], b = s[1];
  us8 o = {f2bf(a.x), f2bf(a.y), f2bf(a.z), f2bf(a.w),
           f2bf(b.x), f2bf(b.y), f2bf(b.z), f2bf(b.w)};
  *(us8*)(xb + (size_t)i * 8) = o;
}

// w1 chunk: [E][FC][HD], source rows contiguous per expert
__global__ void conv_w1c_kernel(const float* __restrict__ w1, unsigned short* __restrict__ wc,
                                int c, int FC) {
  int i = blockIdx.x * 256 + threadIdx.x;
  int per_e = FC * HD;
  int pos = i * 8;
  int e = pos / per_e;
  int rem = pos - e * per_e;
  const float4* s = (const float4*)(w1 + ((size_t)e * FD + (size_t)c * FC) * HD + rem);
  float4 a = s[0], b = s[1];
  us8 o = {f2bf(a.x), f2bf(a.y), f2bf(a.z), f2bf(a.w),
           f2bf(b.x), f2bf(b.y), f2bf(b.z), f2bf(b.w)};
  *(us8*)(wc + (size_t)pos) = o;
}

// w2 chunk: [E][HD][FC], source is an F-slice of each row
__global__ void conv_w2c_kernel(const float* __restrict__ w2, unsigned short* __restrict__ wc,
                                int c, int FC) {
  int i = blockIdx.x * 256 + threadIdx.x;
  int per_e = HD * FC;
  int pos = i * 8;
  int e = pos / per_e;
  int rem = pos - e * per_e;
  int h = rem / FC;
  int f0 = rem - h * FC;
  const float4* s = (const float4*)(w2 + ((size_t)e * HD + h) * FD + (size_t)c * FC + f0);
  float4 a = s[0], b = s[1];
  us8 o = {f2bf(a.x), f2bf(a.y), f2bf(a.z), f2bf(a.w),
           f2bf(b.x), f2bf(b.y), f2bf(b.z), f2bf(b.w)};
  *(us8*)(wc + (size_t)pos) = o;
}

// ---------------- GEMM1: Hc = silu(Xg @ W1c^T) ----------------
// 128x128 tile, BK=32, global_load_lds staging, swizzled LDS.

__global__ __launch_bounds__(256) void gemm1_kernel(
    const unsigned short* __restrict__ xb, const unsigned short* __restrict__ w1c,
    const int* __restrict__ row_token, const int* __restrict__ offsets,
    const int* __restrict__ tile_expert, const int* __restrict__ tile_rowstart,
    const int* __restrict__ total_tiles,
    unsigned short* __restrict__ Hbuf, int FC) {
  int rt = blockIdx.x;
  if (rt >= *total_tiles) return;
  int e = tile_expert[rt];
  int rstart = tile_rowstart[rt];
  int nvalid = offsets[e + 1] - rstart;
  if (nvalid > 128) nvalid = 128;
  int fb = blockIdx.y * 128;

  __shared__ unsigned short Asm[4096];   // 128 rows x 4 slots x 8 bf16
  __shared__ unsigned short Bsm[4096];

  int tid = threadIdx.x, lane = tid & 63, wv = tid >> 6;
  int qA = ((lane & 3) ^ ((lane >> 3) & 3)) * 8;   // swizzled k-quad, elements

  const unsigned short* ag[2];
  const unsigned short* bg[2];
  unsigned short* al[2];
  unsigned short* bl[2];
#pragma unroll
  for (int p = 0; p < 2; ++p) {
    int r = wv * 32 + p * 16 + (lane >> 2);
    int rg = rstart + r;
    if (rg > NP - 1) rg = NP - 1;
    ag[p] = xb + (size_t)row_token[rg] * HD + qA;
    bg[p] = w1c + ((size_t)e * FC + fb + sigma(r)) * HD + qA;
    al[p] = Asm + (wv * 128 + p * 64) * 8;
    bl[p] = Bsm + (wv * 128 + p * 64) * 8;
  }

  f32x4 acc[4][4];
  f32x4 vz = {0.f, 0.f, 0.f, 0.f};
#pragma unroll
  for (int i = 0; i < 4; ++i)
#pragma unroll
    for (int j = 0; j < 4; ++j) acc[i][j] = vz;

  int wm = (wv & 1) * 64, wn = (wv >> 1) * 64;
  int lr = lane & 15;
  int q_sw = (((lane >> 4) ^ ((lr >> 1) & 3))) * 8;

  for (int kb = 0; kb < HD / 32; ++kb) {
    __syncthreads();
#pragma unroll
    for (int p = 0; p < 2; ++p) {
      gll16(ag[p], al[p]);
      gll16(bg[p], bl[p]);
      ag[p] += 32; bg[p] += 32;
    }
    __syncthreads();
    bf16x8 af[4], bfr[4];
#pragma unroll
    for (int i = 0; i < 4; ++i) af[i] = frag_ld(&Asm[(wm + i * 16 + lr) * 32 + q_sw]);
#pragma unroll
    for (int j = 0; j < 4; ++j) bfr[j] = frag_ld(&Bsm[(wn + j * 16 + lr) * 32 + q_sw]);
#pragma unroll
    for (int i = 0; i < 4; ++i)
#pragma unroll
      for (int j = 0; j < 4; ++j)
        acc[i][j] = __builtin_amdgcn_mfma_f32_16x16x32_bf16(af[i], bfr[j], acc[i][j], 0, 0, 0);
  }

  // epilogue: lane owns 4 contiguous cols (sigma permutation) -> ushort4 stores
  int cb = wn + (lane & 15) * 4;
  int rq = (lane >> 4) * 4;
#pragma unroll
  for (int i = 0; i < 4; ++i) {
#pragma unroll
    for (int r = 0; r < 4; ++r) {
      int row = wm + i * 16 + rq + r;
      if (row < nvalid) {
        ushort4 hv;
        hv.x = f2bf(silu(acc[i][0][r]));
        hv.y = f2bf(silu(acc[i][1][r]));
        hv.z = f2bf(silu(acc[i][2][r]));
        hv.w = f2bf(silu(acc[i][3][r]));
        *(ushort4*)&Hbuf[(size_t)(rstart + row) * FC + fb + cb] = hv;
      }
    }
  }
}

// ---------------- GEMM2: Y += diag(w) * (Hc @ W2c^T) ----------------

__global__ __launch_bounds__(256) void gemm2_kernel(
    const unsigned short* __restrict__ Hbuf, const unsigned short* __restrict__ w2c,
    const int* __restrict__ row_token, const float* __restrict__ row_w,
    const int* __restrict__ offsets,
    const int* __restrict__ tile_expert, const int* __restrict__ tile_rowstart,
    const int* __restrict__ total_tiles,
    float* __restrict__ y, int FC) {
  int rt = blockIdx.x;
  if (rt >= *total_tiles) return;
  int e = tile_expert[rt];
  int rstart = tile_rowstart[rt];
  int nvalid = offsets[e + 1] - rstart;
  if (nvalid > 128) nvalid = 128;
  int hb = blockIdx.y * 128;
  int koff = blockIdx.z * (FC / ZS);

  __shared__ unsigned short Asm[4096];
  __shared__ unsigned short Bsm[4096];

  int tid = threadIdx.x, lane = tid & 63, wv = tid >> 6;
  int qA = ((lane & 3) ^ ((lane >> 3) & 3)) * 8;

  const unsigned short* ag[2];
  const unsigned short* bg[2];
  unsigned short* al[2];
  unsigned short* bl[2];
#pragma unroll
  for (int p = 0; p < 2; ++p) {
    int r = wv * 32 + p * 16 + (lane >> 2);
    int rg = rstart + r;
    if (rg > NP - 1) rg = NP - 1;
    ag[p] = Hbuf + (size_t)rg * FC + koff + qA;
    bg[p] = w2c + ((size_t)e * HD + hb + sigma(r)) * FC + koff + qA;
    al[p] = Asm + (wv * 128 + p * 64) * 8;
    bl[p] = Bsm + (wv * 128 + p * 64) * 8;
  }

  f32x4 acc[4][4];
  f32x4 vz = {0.f, 0.f, 0.f, 0.f};
#pragma unroll
  for (int i = 0; i < 4; ++i)
#pragma unroll
    for (int j = 0; j < 4; ++j) acc[i][j] = vz;

  int wm = (wv & 1) * 64, wn = (wv >> 1) * 64;
  int lr = lane & 15;
  int q_sw = (((lane >> 4) ^ ((lr >> 1) & 3))) * 8;

  int iters = FC / (32 * ZS);
  for (int kb = 0; kb < iters; ++kb) {
    __syncthreads();
#pragma unroll
    for (int p = 0; p < 2; ++p) {
      gll16(ag[p], al[p]);
      gll16(bg[p], bl[p]);
      ag[p] += 32; bg[p] += 32;
    }
    __syncthreads();
    bf16x8 af[4], bfr[4];
#pragma unroll
    for (int i = 0; i < 4; ++i) af[i] = frag_ld(&Asm[(wm + i * 16 + lr) * 32 + q_sw]);
#pragma unroll
    for (int j = 0; j < 4; ++j) bfr[j] = frag_ld(&Bsm[(wn + j * 16 + lr) * 32 + q_sw]);
#pragma unroll
    for (int i = 0; i < 4; ++i)
#pragma unroll
      for (int j = 0; j < 4; ++j)
        acc[i][j] = __builtin_amdgcn_mfma_f32_16x16x32_bf16(af[i], bfr[j], acc[i][j], 0, 0, 0);
  }

  int cb = wn + (lane & 15) * 4;
  int rq = (lane >> 4) * 4;
#pragma unroll
  for (int i = 0; i < 4; ++i) {
#pragma unroll
    for (int r = 0; r < 4; ++r) {
      int row = wm + i * 16 + rq + r;
      if (row < nvalid) {
        int rg = rstart + row;
        float wgt = row_w[rg];
        float* yrow = y + (size_t)row_token[rg] * HD + hb + cb;
#pragma unroll
        for (int j = 0; j < 4; ++j)
          atomicAdd(yrow + j, wgt * acc[i][j][r]);
      }
    }
  }
}

// ---------------- host ----------------

extern "C" void kernel_launch(void* const* d_in, const int* in_sizes, int n_in,
                              void* d_out, int out_size, void* d_ws, size_t ws_size,
                              hipStream_t stream) {
  const float* x      = (const float*)d_in[0];
  const int*   topk_e = (const int*)d_in[1];
  const float* topk_w = (const float*)d_in[2];
  const float* w1     = (const float*)d_in[3];
  const float* w2     = (const float*)d_in[4];
  float* y = (float*)d_out;

  char* ws = (char*)d_ws;
  int* counts        = (int*)(ws + 0);
  int* cursors       = (int*)(ws + 64);
  int* offsets       = (int*)(ws + 128);
  int* total_tiles   = (int*)(ws + 192);
  int* tile_expert   = (int*)(ws + 256);
  int* tile_rowstart = (int*)(ws + 1024);
  int* row_token     = (int*)(ws + 4096);
  float* row_w       = (float*)(ws + 4096 + (size_t)NP * 4);
  size_t hdr = 4096 + (size_t)NP * 8;

  unsigned short* xb = (unsigned short*)(ws + hdr);
  size_t xbytes = (size_t)SS * HD * 2;

  // largest F-chunk whose (shared weight scratch + bf16 H buffer) fits
  int FC = FD;
  while (FC > 256) {
    size_t need = hdr + xbytes + (size_t)NE * FC * HD * 2 + (size_t)NP * FC * 2;
    if (need <= ws_size) break;
    FC >>= 1;
  }
  unsigned short* wc = xb + (size_t)SS * HD;
  unsigned short* Hbuf = wc + (size_t)NE * FC * HD;

  hipMemsetAsync(d_out, 0, (size_t)SS * HD * sizeof(float), stream);
  hipMemsetAsync(d_ws, 0, 2048, stream);

  count_kernel<<<NP / 256, 256, 0, stream>>>(topk_e, counts);
  plan_kernel<<<1, 1, 0, stream>>>(counts, offsets, cursors, tile_expert, tile_rowstart, total_tiles);
  scatter_kernel<<<NP / 256, 256, 0, stream>>>(topk_e, topk_w, cursors, row_token, row_w);
  conv_x_kernel<<<SS * HD / 8 / 256, 256, 0, stream>>>(x, xb);

  int nchunks = FD / FC;
  int wblocks = FC * HD / 8 / 256 * NE;   // = FC*4 when HD=1024... (NE*FC*HD/8/256)
  for (int c = 0; c < nchunks; ++c) {
    conv_w1c_kernel<<<wblocks, 256, 0, stream>>>(w1, wc, c, FC);
    gemm1_kernel<<<dim3(MAX_TILES, FC / 128), 256, 0, stream>>>(
        xb, wc, row_token, offsets, tile_expert, tile_rowstart, total_tiles, Hbuf, FC);
    // wc is free again once gemm1 completes (stream-ordered): reuse for w2 chunk
    conv_w2c_kernel<<<wblocks, 256, 0, stream>>>(w2, wc, c, FC);
    gemm2_kernel<<<dim3(MAX_TILES, HD / 128, ZS), 256, 0, stream>>>(
        Hbuf, wc, row_token, row_w, offsets, tile_expert, tile_rowstart, total_tiles, y, FC);
  }
}

// Round 3
// 733.524 us; speedup vs baseline: 1.5616x; 1.5616x over previous
//
#include <hip/hip_runtime.h>
#include <hip/hip_bf16.h>

// MoE expert MLP, grouped-GEMM formulation:
//   - all operands pre-converted to bf16 (chunked weight scratch reused on-stream)
//   - global_load_lds width=16 staging, BK=64 K-loop (half the barrier drains),
//     8-quad XOR swizzle (qslot = q ^ (row&7)) -> conflict-free ds_read_b128
//   - sigma B-row permutation: each lane owns 4 contiguous output columns
//   - NO atomics: gemm2 stores to pair-indexed Yp, combine kernel applies
//     topk weights (atomic WRITE_SIZE blowup in r2: 524 MB -> ~70 MB)

#define SS 8192
#define HD 1024
#define FD 4096
#define NE 8
#define TK 2
#define NP (SS * TK)
#define MAX_TILES (NP / 128 + NE)

typedef __bf16 bf16x8 __attribute__((ext_vector_type(8)));
typedef unsigned short us8 __attribute__((ext_vector_type(8)));
typedef float f32x4 __attribute__((ext_vector_type(4)));
typedef unsigned int u32;

static __device__ __forceinline__ unsigned short f2bf(float f) {
  union { float f; unsigned u; } v; v.f = f;
  return (unsigned short)((v.u + 0x7fffu + ((v.u >> 16) & 1u)) >> 16);  // RNE
}

static __device__ __forceinline__ bf16x8 frag_ld(const unsigned short* p) {
  union { us8 u; bf16x8 b; } v;
  v.u = *(const us8*)p;
  return v.b;
}

static __device__ __forceinline__ void gll16(const void* g, void* l) {
  __builtin_amdgcn_global_load_lds(
      (const __attribute__((address_space(1))) u32*)g,
      (__attribute__((address_space(3))) u32*)l, 16, 0, 0);
}

static __device__ __forceinline__ float silu(float v) {
  return v / (1.f + __expf(-v));
}

// sigma: B-row permutation within each 64-row half: sigma(h*64+16q+l) = h*64+4l+q
static __device__ __forceinline__ int sigma(int r) {
  return (r & 64) + ((r & 15) * 4) + ((r >> 4) & 3);
}

// ---------------- bucket building ----------------

__global__ void count_kernel(const int* __restrict__ topk_e, int* __restrict__ counts) {
  __shared__ int lc[NE];
  int tid = threadIdx.x;
  if (tid < NE) lc[tid] = 0;
  __syncthreads();
  atomicAdd(&lc[topk_e[blockIdx.x * 256 + tid]], 1);
  __syncthreads();
  if (tid < NE) atomicAdd(&counts[tid], lc[tid]);
}

__global__ void plan_kernel(const int* __restrict__ counts, int* __restrict__ offsets,
                            int* __restrict__ cursors, int* __restrict__ tile_expert,
                            int* __restrict__ tile_rowstart, int* __restrict__ total_tiles) {
  if (threadIdx.x != 0 || blockIdx.x != 0) return;
  int off = 0, tt = 0;
  for (int e = 0; e < NE; ++e) {
    offsets[e] = off;
    cursors[e] = off;
    int n = counts[e];
    int nt = (n + 127) >> 7;
    for (int i = 0; i < nt; ++i) {
      tile_expert[tt] = e;
      tile_rowstart[tt] = off + i * 128;
      ++tt;
    }
    off += n;
  }
  offsets[NE] = off;
  *total_tiles = tt;
}

__global__ void scatter_kernel(const int* __restrict__ topk_e, const float* __restrict__ topk_w,
                               int* __restrict__ cursors, int* __restrict__ row_token,
                               int* __restrict__ inv) {
  __shared__ int lcnt[NE];
  __shared__ int lbase[NE];
  int tid = threadIdx.x;
  if (tid < NE) lcnt[tid] = 0;
  __syncthreads();
  int t = blockIdx.x * 256 + tid;
  int e = topk_e[t];
  int my = atomicAdd(&lcnt[e], 1);
  __syncthreads();
  if (tid < NE) lbase[tid] = atomicAdd(&cursors[tid], lcnt[tid]);
  __syncthreads();
  int pos = lbase[e] + my;
  row_token[pos] = t / TK;
  inv[t] = pos;
}

// ---------------- fp32 -> bf16 converts ----------------

__global__ void conv_x_kernel(const float* __restrict__ x, unsigned short* __restrict__ xb) {
  int i = blockIdx.x * 256 + threadIdx.x;      // one thread per 8 floats
  const float4* s = (const float4*)(x + (size_t)i * 8);
  float4 a = s[0], b = s[1];
  us8 o = {f2bf(a.x), f2bf(a.y), f2bf(a.z), f2bf(a.w),
           f2bf(b.x), f2bf(b.y), f2bf(b.z), f2bf(b.w)};
  *(us8*)(xb + (size_t)i * 8) = o;
}

// w1 chunk: [E][FC][HD], source rows contiguous per expert
__global__ void conv_w1c_kernel(const float* __restrict__ w1, unsigned short* __restrict__ wc,
                                int c, int FC) {
  int i = blockIdx.x * 256 + threadIdx.x;
  int per_e = FC * HD;
  int pos = i * 8;
  int e = pos / per_e;
  int rem = pos - e * per_e;
  const float4* s = (const float4*)(w1 + ((size_t)e * FD + (size_t)c * FC) * HD + rem);
  float4 a = s[0], b = s[1];
  us8 o = {f2bf(a.x), f2bf(a.y), f2bf(a.z), f2bf(a.w),
           f2bf(b.x), f2bf(b.y), f2bf(b.z), f2bf(b.w)};
  *(us8*)(wc + (size_t)pos) = o;
}

// w2 chunk: [E][HD][FC], source is an F-slice of each row
__global__ void conv_w2c_kernel(const float* __restrict__ w2, unsigned short* __restrict__ wc,
                                int c, int FC) {
  int i = blockIdx.x * 256 + threadIdx.x;
  int per_e = HD * FC;
  int pos = i * 8;
  int e = pos / per_e;
  int rem = pos - e * per_e;
  int h = rem / FC;
  int f0 = rem - h * FC;
  const float4* s = (const float4*)(w2 + ((size_t)e * HD + h) * FD + (size_t)c * FC + f0);
  float4 a = s[0], b = s[1];
  us8 o = {f2bf(a.x), f2bf(a.y), f2bf(a.z), f2bf(a.w),
           f2bf(b.x), f2bf(b.y), f2bf(b.z), f2bf(b.w)};
  *(us8*)(wc + (size_t)pos) = o;
}

// ---------------- GEMM1: Hc = silu(Xg @ W1c^T) ----------------
// 128x128 tile, BK=64, global_load_lds staging, 8-quad swizzled LDS.
// LDS slot s = row*8 + qslot holds k-quad q = qslot ^ (row&7) of that row.

__global__ __launch_bounds__(256) void gemm1_kernel(
    const unsigned short* __restrict__ xb, const unsigned short* __restrict__ w1c,
    const int* __restrict__ row_token, const int* __restrict__ offsets,
    const int* __restrict__ tile_expert, const int* __restrict__ tile_rowstart,
    const int* __restrict__ total_tiles,
    unsigned short* __restrict__ Hbuf, int FC) {
  int rt = blockIdx.x;
  if (rt >= *total_tiles) return;
  int e = tile_expert[rt];
  int rstart = tile_rowstart[rt];
  int nvalid = offsets[e + 1] - rstart;
  if (nvalid > 128) nvalid = 128;
  int fb = blockIdx.y * 128;

  __shared__ unsigned short Asm[8192];   // 128 rows x 8 slots x 8 bf16 = 16 KB
  __shared__ unsigned short Bsm[8192];

  int tid = threadIdx.x, lane = tid & 63, wv = tid >> 6;
  int qel = ((lane & 7) ^ ((lane >> 3) & 7)) * 8;   // source k-quad (elements)

  const unsigned short* ag[4];
  const unsigned short* bg[4];
#pragma unroll
  for (int p = 0; p < 4; ++p) {
    int r = p * 32 + wv * 8 + (lane >> 3);
    int rg = rstart + r;
    if (rg > NP - 1) rg = NP - 1;
    ag[p] = xb + (size_t)row_token[rg] * HD + qel;
    bg[p] = w1c + ((size_t)e * FC + fb + sigma(r)) * HD + qel;
  }

  f32x4 acc[4][4];
  f32x4 vz = {0.f, 0.f, 0.f, 0.f};
#pragma unroll
  for (int i = 0; i < 4; ++i)
#pragma unroll
    for (int j = 0; j < 4; ++j) acc[i][j] = vz;

  int wm = (wv & 1) * 64, wn = (wv >> 1) * 64;
  int lr = lane & 15;

  for (int kb = 0; kb < HD / 64; ++kb) {
    __syncthreads();
#pragma unroll
    for (int p = 0; p < 4; ++p) {
      gll16(ag[p], Asm + (p * 256 + wv * 64) * 8);
      gll16(bg[p], Bsm + (p * 256 + wv * 64) * 8);
      ag[p] += 64; bg[p] += 64;
    }
    __syncthreads();
#pragma unroll
    for (int t = 0; t < 2; ++t) {
      int qsl = ((t * 4 + (lane >> 4)) ^ (lr & 7)) * 8;
      bf16x8 af[4], bfr[4];
#pragma unroll
      for (int i = 0; i < 4; ++i) af[i] = frag_ld(&Asm[(wm + i * 16 + lr) * 64 + qsl]);
#pragma unroll
      for (int j = 0; j < 4; ++j) bfr[j] = frag_ld(&Bsm[(wn + j * 16 + lr) * 64 + qsl]);
#pragma unroll
      for (int i = 0; i < 4; ++i)
#pragma unroll
        for (int j = 0; j < 4; ++j)
          acc[i][j] = __builtin_amdgcn_mfma_f32_16x16x32_bf16(af[i], bfr[j], acc[i][j], 0, 0, 0);
    }
  }

  // epilogue: lane owns 4 contiguous cols (sigma permutation) -> ushort4 stores
  int cb = wn + (lane & 15) * 4;
  int rq = (lane >> 4) * 4;
#pragma unroll
  for (int i = 0; i < 4; ++i) {
#pragma unroll
    for (int r = 0; r < 4; ++r) {
      int row = wm + i * 16 + rq + r;
      if (row < nvalid) {
        ushort4 hv;
        hv.x = f2bf(silu(acc[i][0][r]));
        hv.y = f2bf(silu(acc[i][1][r]));
        hv.z = f2bf(silu(acc[i][2][r]));
        hv.w = f2bf(silu(acc[i][3][r]));
        *(ushort4*)&Hbuf[(size_t)(rstart + row) * FC + fb + cb] = hv;
      }
    }
  }
}

// ---------------- GEMM2: Yp = Hc @ W2c^T (pair rows, no weights, no atomics) ----------------

__global__ __launch_bounds__(256) void gemm2_kernel(
    const unsigned short* __restrict__ Hbuf, const unsigned short* __restrict__ w2c,
    const int* __restrict__ offsets,
    const int* __restrict__ tile_expert, const int* __restrict__ tile_rowstart,
    const int* __restrict__ total_tiles,
    float* __restrict__ Yp, int FC, int first) {
  int rt = blockIdx.x;
  if (rt >= *total_tiles) return;
  int e = tile_expert[rt];
  int rstart = tile_rowstart[rt];
  int nvalid = offsets[e + 1] - rstart;
  if (nvalid > 128) nvalid = 128;
  int hb = blockIdx.y * 128;

  __shared__ unsigned short Asm[8192];
  __shared__ unsigned short Bsm[8192];

  int tid = threadIdx.x, lane = tid & 63, wv = tid >> 6;
  int qel = ((lane & 7) ^ ((lane >> 3) & 7)) * 8;

  const unsigned short* ag[4];
  const unsigned short* bg[4];
#pragma unroll
  for (int p = 0; p < 4; ++p) {
    int r = p * 32 + wv * 8 + (lane >> 3);
    int rg = rstart + r;
    if (rg > NP - 1) rg = NP - 1;
    ag[p] = Hbuf + (size_t)rg * FC + qel;
    bg[p] = w2c + ((size_t)e * HD + hb + sigma(r)) * FC + qel;
  }

  f32x4 acc[4][4];
  f32x4 vz = {0.f, 0.f, 0.f, 0.f};
#pragma unroll
  for (int i = 0; i < 4; ++i)
#pragma unroll
    for (int j = 0; j < 4; ++j) acc[i][j] = vz;

  int wm = (wv & 1) * 64, wn = (wv >> 1) * 64;
  int lr = lane & 15;

  for (int kb = 0; kb < FC / 64; ++kb) {
    __syncthreads();
#pragma unroll
    for (int p = 0; p < 4; ++p) {
      gll16(ag[p], Asm + (p * 256 + wv * 64) * 8);
      gll16(bg[p], Bsm + (p * 256 + wv * 64) * 8);
      ag[p] += 64; bg[p] += 64;
    }
    __syncthreads();
#pragma unroll
    for (int t = 0; t < 2; ++t) {
      int qsl = ((t * 4 + (lane >> 4)) ^ (lr & 7)) * 8;
      bf16x8 af[4], bfr[4];
#pragma unroll
      for (int i = 0; i < 4; ++i) af[i] = frag_ld(&Asm[(wm + i * 16 + lr) * 64 + qsl]);
#pragma unroll
      for (int j = 0; j < 4; ++j) bfr[j] = frag_ld(&Bsm[(wn + j * 16 + lr) * 64 + qsl]);
#pragma unroll
      for (int i = 0; i < 4; ++i)
#pragma unroll
        for (int j = 0; j < 4; ++j)
          acc[i][j] = __builtin_amdgcn_mfma_f32_16x16x32_bf16(af[i], bfr[j], acc[i][j], 0, 0, 0);
    }
  }

  int cb = wn + (lane & 15) * 4;
  int rq = (lane >> 4) * 4;
#pragma unroll
  for (int i = 0; i < 4; ++i) {
#pragma unroll
    for (int r = 0; r < 4; ++r) {
      int row = wm + i * 16 + rq + r;
      if (row < nvalid) {
        float* dst = Yp + (size_t)(rstart + row) * HD + hb + cb;
        float4 v;
        v.x = acc[i][0][r]; v.y = acc[i][1][r]; v.z = acc[i][2][r]; v.w = acc[i][3][r];
        if (!first) {
          float4 o = *(const float4*)dst;
          v.x += o.x; v.y += o.y; v.z += o.z; v.w += o.w;
        }
        *(float4*)dst = v;
      }
    }
  }
}

// ---------------- combine: y[s] = sum_k topk_w[s,k] * Yp[inv[s*2+k]] ----------------
// one block per token row: fully coalesced 4 KB reads/writes.

__global__ void combine_kernel(const float* __restrict__ Yp, const int* __restrict__ inv,
                               const float* __restrict__ topk_w, float* __restrict__ y) {
  int s = blockIdx.x;
  int c = threadIdx.x * 4;
  int i0 = inv[s * 2], i1 = inv[s * 2 + 1];
  float w0 = topk_w[s * 2], w1 = topk_w[s * 2 + 1];
  float4 a = *(const float4*)(Yp + (size_t)i0 * HD + c);
  float4 b = *(const float4*)(Yp + (size_t)i1 * HD + c);
  float4 o;
  o.x = w0 * a.x + w1 * b.x;
  o.y = w0 * a.y + w1 * b.y;
  o.z = w0 * a.z + w1 * b.z;
  o.w = w0 * a.w + w1 * b.w;
  *(float4*)(y + (size_t)s * HD + c) = o;
}

// ---------------- host ----------------

extern "C" void kernel_launch(void* const* d_in, const int* in_sizes, int n_in,
                              void* d_out, int out_size, void* d_ws, size_t ws_size,
                              hipStream_t stream) {
  const float* x      = (const float*)d_in[0];
  const int*   topk_e = (const int*)d_in[1];
  const float* topk_w = (const float*)d_in[2];
  const float* w1     = (const float*)d_in[3];
  const float* w2     = (const float*)d_in[4];
  float* y = (float*)d_out;

  char* ws = (char*)d_ws;
  int* counts        = (int*)(ws + 0);
  int* cursors       = (int*)(ws + 64);
  int* offsets       = (int*)(ws + 128);
  int* total_tiles   = (int*)(ws + 192);
  int* tile_expert   = (int*)(ws + 256);
  int* tile_rowstart = (int*)(ws + 1024);
  int* row_token     = (int*)(ws + 4096);
  int* inv           = (int*)(ws + 4096 + (size_t)NP * 4);
  size_t hdr = 4096 + (size_t)NP * 8;

  unsigned short* xb = (unsigned short*)(ws + hdr);
  size_t xbytes = (size_t)SS * HD * 2;
  size_t ypbytes = (size_t)NP * HD * 4;

  // largest F-chunk whose (weight scratch + bf16 H buffer + Yp) fits
  int FC = FD;
  while (FC > 256) {
    size_t need = hdr + xbytes + (size_t)NE * FC * HD * 2 + (size_t)NP * FC * 2 + ypbytes;
    if (need <= ws_size) break;
    FC >>= 1;
  }
  unsigned short* wc = xb + (size_t)SS * HD;
  unsigned short* Hbuf = wc + (size_t)NE * FC * HD;
  float* Yp = (float*)(Hbuf + (size_t)NP * FC);

  hipMemsetAsync(d_ws, 0, 2048, stream);

  count_kernel<<<NP / 256, 256, 0, stream>>>(topk_e, counts);
  plan_kernel<<<1, 1, 0, stream>>>(counts, offsets, cursors, tile_expert, tile_rowstart, total_tiles);
  scatter_kernel<<<NP / 256, 256, 0, stream>>>(topk_e, topk_w, cursors, row_token, inv);
  conv_x_kernel<<<SS * HD / 8 / 256, 256, 0, stream>>>(x, xb);

  int nchunks = FD / FC;
  int wblocks = (int)((size_t)NE * FC * HD / 8 / 256);
  for (int c = 0; c < nchunks; ++c) {
    conv_w1c_kernel<<<wblocks, 256, 0, stream>>>(w1, wc, c, FC);
    gemm1_kernel<<<dim3(MAX_TILES, FC / 128), 256, 0, stream>>>(
        xb, wc, row_token, offsets, tile_expert, tile_rowstart, total_tiles, Hbuf, FC);
    // wc is free again once gemm1 completes (stream-ordered): reuse for w2 chunk
    conv_w2c_kernel<<<wblocks, 256, 0, stream>>>(w2, wc, c, FC);
    gemm2_kernel<<<dim3(MAX_TILES, HD / 128), 256, 0, stream>>>(
        Hbuf, wc, offsets, tile_expert, tile_rowstart, total_tiles, Yp, FC, c == 0 ? 1 : 0);
  }
  combine_kernel<<<SS, 256, 0, stream>>>(Yp, inv, topk_w, y);
}